// Round 7
// baseline (1429.502 us; speedup 1.0000x reference)
//
#include <hip/hip_runtime.h>
#include <hip/hip_fp16.h>
#include <stdint.h>

// ---------------------------------------------------------------------------
// Seq2SeqARDiffusion on MI355X.
//   k_prep_xh  : pack [x_hist|emb] fp16 inputs for LSTM0
//   k_prep_w   : pack LSTM weights into MFMA A-fragment order (+ W2, bias sums)
//   k_lstm0    : persistent MFMA LSTM layer 0, 64 WGs x 512 thr, 16 batch/WG
//   k_lstm1    : persistent MFMA LSTM layer 1 -> enc_out
//   k_prep_diff: fold enc/emb/exo/hproj/b1 into baseS[b][s][k] (f32 acc),
//                tproj/cc/w1y/w150 tables  (aliases dead xh16 region)
//   k_diff     : 32 WGs x 64 thr (SINGLE WAVE), 2 chains x 16 batches/wave,
//                BARRIER-FREE t-loop: full n=128 per wave (8 n-tiles MFMA),
//                b2 folded into MFMA C-operand, eps via DPP rowsum + shfl.
// ---------------------------------------------------------------------------

typedef __attribute__((ext_vector_type(2))) _Float16 half2_t;
typedef __attribute__((ext_vector_type(8))) _Float16 v8h;
typedef __attribute__((ext_vector_type(4))) float v4f;

#define DEV __device__ __forceinline__

// Barrier with LDS-only drain (skips vmcnt(0) drain of __syncthreads).
DEV void barrier_lds() {
  asm volatile("s_waitcnt lgkmcnt(0)\ns_barrier" ::: "memory");
}

DEV uint32_t pack2f(float a, float b) {
  __half ha = __float2half_rn(a), hb = __float2half_rn(b);
  return (uint32_t)__half_as_ushort(ha) | ((uint32_t)__half_as_ushort(hb) << 16);
}

DEV float fast_ex2(float x) {
#if __has_builtin(__builtin_amdgcn_exp2f)
  return __builtin_amdgcn_exp2f(x);
#else
  return exp2f(x);
#endif
}
DEV float fast_rcp(float x) {
#if __has_builtin(__builtin_amdgcn_rcpf)
  return __builtin_amdgcn_rcpf(x);
#else
  return 1.f / x;
#endif
}
DEV float sigm(float x) { return fast_rcp(1.f + fast_ex2(-1.4426950408889634f * x)); }
DEV float tanh_f(float x) {
  return 2.f * fast_rcp(1.f + fast_ex2(-2.8853900817779268f * x)) - 1.f;
}

DEV uint32_t pk_add(uint32_t a, uint32_t b) {
  return __builtin_bit_cast(uint32_t,
      __builtin_bit_cast(half2_t, a) + __builtin_bit_cast(half2_t, b));
}

// w*y + b, packed fp16
DEV uint32_t pk_fma(uint32_t w, uint32_t y, uint32_t b) {
  return __builtin_bit_cast(uint32_t,
      __builtin_bit_cast(half2_t, w) * __builtin_bit_cast(half2_t, y) +
      __builtin_bit_cast(half2_t, b));
}

// relu(w*y + b), packed fp16
DEV uint32_t pk_relufma(uint32_t w, uint32_t y, uint32_t b) {
  half2_t r = __builtin_bit_cast(half2_t, w) * __builtin_bit_cast(half2_t, y) +
              __builtin_bit_cast(half2_t, b);
  half2_t z = {(_Float16)0.f, (_Float16)0.f};
#if __has_builtin(__builtin_elementwise_max)
  r = __builtin_elementwise_max(r, z);
#else
  uint32_t u = __builtin_bit_cast(uint32_t, r);
  uint32_t mask = ((u >> 15) & 1u) * 0xFFFFu | ((u >> 31) & 1u) * 0xFFFF0000u;
  r = __builtin_bit_cast(half2_t, u & ~mask);
#endif
  return __builtin_bit_cast(uint32_t, r);
}

DEV uint32_t cvtpk(float y) {
#if __has_builtin(__builtin_amdgcn_cvt_pkrtz)
  return __builtin_bit_cast(uint32_t, __builtin_amdgcn_cvt_pkrtz(y, y));
#else
  return pack2f(y, y);
#endif
}

// sum within each 16-lane row; lane (l&15)==15 holds the row sum
DEV float rowsum16(float v) {
  int x;
  x = __builtin_amdgcn_update_dpp(0, __builtin_bit_cast(int, v), 0x111, 0xf, 0xf, true);
  v += __builtin_bit_cast(float, x);
  x = __builtin_amdgcn_update_dpp(0, __builtin_bit_cast(int, v), 0x112, 0xf, 0xf, true);
  v += __builtin_bit_cast(float, x);
  x = __builtin_amdgcn_update_dpp(0, __builtin_bit_cast(int, v), 0x114, 0xf, 0xf, true);
  v += __builtin_bit_cast(float, x);
  x = __builtin_amdgcn_update_dpp(0, __builtin_bit_cast(int, v), 0x118, 0xf, 0xf, true);
  v += __builtin_bit_cast(float, x);
  return v;
}

// ---------------- workspace layout (bytes) ----------------
static constexpr size_t OFF_XH  = 0;                 // 96*1024*12 u32 = 4,718,592
static constexpr size_t OFF_W0  = 4718592;           // w0A 40960 u32 = 163,840
static constexpr size_t OFF_BS0 = 4882432;           // 512 f32
static constexpr size_t OFF_W1L = 4884480;           // w1A 65536 u32 = 262,144
static constexpr size_t OFF_BS1 = 5146624;           // 512 f32
static constexpr size_t OFF_W2P = 5148672;           // 128*64 u32 = 32,768
static constexpr size_t OFF_ENC = 5181440;           // 1024*128 f32 = 524,288
static constexpr size_t OFF_YS0 = 5705728;           // 96*1024*128 half = 25,165,824
// aliased into the dead xh16 region (xh16 only live until k_lstm0):
static constexpr size_t OFF_BASES = 0;               // half[1024*8*128] = 2,097,152
static constexpr size_t OFF_TPROJ = 2097152;         // half[100*128] = 25,600
static constexpr size_t OFF_CC    = 2122752;         // float2[100] = 800
static constexpr size_t OFF_W1YP  = 2123584;         // u32[64]
static constexpr size_t OFF_W150P = 2123840;         // u32[64]

// ---------------- prep: pack [x_hist | emb] as fp16 pairs ----------------
__global__ void k_prep_xh(const float* __restrict__ xh, const int* __restrict__ tix,
                          const float* __restrict__ temb, uint32_t* __restrict__ out) {
  int idx = blockIdx.x * 256 + threadIdx.x;          // 96*1024*12 total
  if (idx >= 96 * 1024 * 12) return;
  int m = idx % 12;
  int tb = idx / 12;
  int b = tb & 1023, t = tb >> 10;
  int k0 = 2 * m, k1 = k0 + 1;
  float v0 = (k0 < 8) ? xh[(b * 96 + t) * 8 + k0] : temb[tix[b] * 16 + (k0 - 8)];
  float v1 = (k1 < 8) ? xh[(b * 96 + t) * 8 + k1] : temb[tix[b] * 16 + (k1 - 8)];
  out[idx] = pack2f(v0, v1);
}

// ---------------- prep: pack LSTM/W2 weights ----------------
__global__ void k_prep_w(const float* __restrict__ Wih0, const float* __restrict__ Whh0,
                         const float* __restrict__ bih0, const float* __restrict__ bhh0,
                         const float* __restrict__ Wih1, const float* __restrict__ Whh1,
                         const float* __restrict__ bih1, const float* __restrict__ bhh1,
                         const float* __restrict__ W2,
                         uint32_t* __restrict__ w0p, uint32_t* __restrict__ w1p,
                         uint32_t* __restrict__ w2p, float* __restrict__ bs0,
                         float* __restrict__ bs1) {
  int idx = blockIdx.x * 256 + threadIdx.x;
  if (idx < 40960) {                       // w0A: NF=5, K=160 ([x24|h128|pad8])
    int w = idx / 5120;
    int r = idx % 5120;
    int T = r / 1280; r %= 1280;
    int f = r / 256;  r %= 256;
    int l = r >> 2, c = r & 3;
    int m = l & 15, qf = l >> 4;
    int g = (m & 3) * 128 + w * 16 + (m >> 2) * 4 + T;
    int k0 = f * 32 + qf * 8 + 2 * c, k1 = k0 + 1;
    float a = (k0 < 24) ? Wih0[g * 24 + k0] : ((k0 < 152) ? Whh0[g * 128 + k0 - 24] : 0.f);
    float b = (k1 < 24) ? Wih0[g * 24 + k1] : ((k1 < 152) ? Whh0[g * 128 + k1 - 24] : 0.f);
    w0p[idx] = pack2f(a, b);
  } else if (idx < 106496) {               // w1A: NF=8, K=256 ([ys0 128|h128])
    int i = idx - 40960;
    int w = i / 8192;
    int r = i % 8192;
    int T = r / 2048; r %= 2048;
    int f = r / 256;  r %= 256;
    int l = r >> 2, c = r & 3;
    int m = l & 15, qf = l >> 4;
    int g = (m & 3) * 128 + w * 16 + (m >> 2) * 4 + T;
    int k0 = f * 32 + qf * 8 + 2 * c, k1 = k0 + 1;
    float a = (k0 < 128) ? Wih1[g * 128 + k0] : Whh1[g * 128 + k0 - 128];
    float b = (k1 < 128) ? Wih1[g * 128 + k1] : Whh1[g * 128 + k1 - 128];
    w1p[i] = pack2f(a, b);
  } else if (idx < 114688) {               // W2: 128 x 64 u32 (row-major pairs)
    int i = idx - 106496;
    w2p[i] = pack2f(W2[2 * i], W2[2 * i + 1]);
  } else if (idx < 115200) {
    int i = idx - 114688;
    bs0[i] = bih0[i] + bhh0[i];
  } else if (idx < 115712) {
    int i = idx - 115200;
    bs1[i] = bih1[i] + bhh1[i];
  }
}

// ---------------- LSTM layer 0 (MFMA; 16 batch/WG, 64 WGs x 512) ----------------
__global__ __launch_bounds__(512, 2) void k_lstm0(const uint32_t* __restrict__ xh16,
                                                  const uint32_t* __restrict__ w0A,
                                                  const float* __restrict__ bs0,
                                                  __half* __restrict__ ys0) {
  __shared__ __align__(16) __half inb[2][16][160];
  const int tid = threadIdx.x;
  const int w = tid >> 6, l = tid & 63;
  const int n = l & 15, ql = l >> 4;
  const int ju = w * 16 + ql * 4;
  const int bbase = blockIdx.x * 16;

  uint4 Af[4][5];
#pragma unroll
  for (int T = 0; T < 4; T++)
#pragma unroll
    for (int f = 0; f < 5; f++)
      Af[T][f] = ((const uint4*)w0A)[((w * 4 + T) * 5 + f) * 64 + l];
  float bias[4][4];
#pragma unroll
  for (int T = 0; T < 4; T++)
#pragma unroll
    for (int r = 0; r < 4; r++) bias[T][r] = bs0[r * 128 + ju + T];

  for (int i = tid; i < 2560; i += 512) ((uint32_t*)inb)[i] = 0u;
  __syncthreads();
  if (tid < 192) {
    int b = tid / 12, m = tid % 12;
    ((uint32_t*)&inb[0][b][0])[m] = xh16[(0 * 1024 + bbase + b) * 12 + m];
  }
  float cst[4] = {0.f, 0.f, 0.f, 0.f};
  __syncthreads();

  for (int t = 0; t < 96; t++) {
    const int cur = t & 1, nxt = cur ^ 1;
    uint32_t sx = 0;
    int sb = 0, sm = 0;
    if (t < 95 && tid < 192) {
      sb = tid / 12; sm = tid % 12;
      sx = xh16[((t + 1) * 1024 + bbase + sb) * 12 + sm];
    }
    v4f acc[4];
#pragma unroll
    for (int T = 0; T < 4; T++) acc[T] = (v4f){0.f, 0.f, 0.f, 0.f};
#pragma unroll
    for (int f = 0; f < 5; f++) {
      uint4 bu = *(const uint4*)&inb[cur][n][f * 32 + ql * 8];
      v8h Bv = __builtin_bit_cast(v8h, bu);
#pragma unroll
      for (int T = 0; T < 4; T++)
        acc[T] = __builtin_amdgcn_mfma_f32_16x16x32_f16(
            __builtin_bit_cast(v8h, Af[T][f]), Bv, acc[T], 0, 0, 0);
    }
    float hv[4];
#pragma unroll
    for (int T = 0; T < 4; T++) {
      float gi = acc[T][0] + bias[T][0];
      float gf = acc[T][1] + bias[T][1];
      float gg = acc[T][2] + bias[T][2];
      float go = acc[T][3] + bias[T][3];
      float c = sigm(gf) * cst[T] + sigm(gi) * tanh_f(gg);
      cst[T] = c;
      hv[T] = sigm(go) * tanh_f(c);
    }
    uint32_t h01 = pack2f(hv[0], hv[1]), h23 = pack2f(hv[2], hv[3]);
    *(uint2*)&inb[nxt][n][24 + ju] = make_uint2(h01, h23);
    *(uint2*)((__half*)ys0 + (size_t)(t * 1024 + bbase + n) * 128 + ju) = make_uint2(h01, h23);
    if (t < 95 && tid < 192) ((uint32_t*)&inb[nxt][sb][0])[sm] = sx;
    barrier_lds();
  }
}

// ---------------- LSTM layer 1 (MFMA; 16 batch/WG, 64 WGs x 512) ----------------
__global__ __launch_bounds__(512, 2) void k_lstm1(const uint32_t* __restrict__ ys0u,
                                                  const uint32_t* __restrict__ w1A,
                                                  const float* __restrict__ bs1,
                                                  float* __restrict__ enc) {
  __shared__ __align__(16) __half inb[2][16][264];
  const int tid = threadIdx.x;
  const int w = tid >> 6, l = tid & 63;
  const int n = l & 15, ql = l >> 4;
  const int ju = w * 16 + ql * 4;
  const int bbase = blockIdx.x * 16;
  const int sb = tid >> 5, sc = tid & 31;

  uint4 Af[4][8];
#pragma unroll
  for (int T = 0; T < 4; T++)
#pragma unroll
    for (int f = 0; f < 8; f++)
      Af[T][f] = ((const uint4*)w1A)[((w * 4 + T) * 8 + f) * 64 + l];
  float bias[4][4];
#pragma unroll
  for (int T = 0; T < 4; T++)
#pragma unroll
    for (int r = 0; r < 4; r++) bias[T][r] = bs1[r * 128 + ju + T];

  for (int i = tid; i < 4224; i += 512) ((uint32_t*)inb)[i] = 0u;
  __syncthreads();
  {
    uint2 v = ((const uint2*)ys0u)[(size_t)(0 * 1024 + bbase + sb) * 32 + sc];
    *(uint2*)&inb[0][sb][sc * 4] = v;
  }
  float cst[4] = {0.f, 0.f, 0.f, 0.f};
  __syncthreads();

  for (int t = 0; t < 96; t++) {
    const int cur = t & 1, nxt = cur ^ 1;
    uint2 sv = make_uint2(0u, 0u);
    if (t < 95)
      sv = ((const uint2*)ys0u)[(size_t)((t + 1) * 1024 + bbase + sb) * 32 + sc];
    v4f acc[4];
#pragma unroll
    for (int T = 0; T < 4; T++) acc[T] = (v4f){0.f, 0.f, 0.f, 0.f};
#pragma unroll
    for (int f = 0; f < 8; f++) {
      uint4 bu = *(const uint4*)&inb[cur][n][f * 32 + ql * 8];
      v8h Bv = __builtin_bit_cast(v8h, bu);
#pragma unroll
      for (int T = 0; T < 4; T++)
        acc[T] = __builtin_amdgcn_mfma_f32_16x16x32_f16(
            __builtin_bit_cast(v8h, Af[T][f]), Bv, acc[T], 0, 0, 0);
    }
    float hv[4];
#pragma unroll
    for (int T = 0; T < 4; T++) {
      float gi = acc[T][0] + bias[T][0];
      float gf = acc[T][1] + bias[T][1];
      float gg = acc[T][2] + bias[T][2];
      float go = acc[T][3] + bias[T][3];
      float c = sigm(gf) * cst[T] + sigm(gi) * tanh_f(gg);
      cst[T] = c;
      hv[T] = sigm(go) * tanh_f(c);
    }
    *(uint2*)&inb[nxt][n][128 + ju] = make_uint2(pack2f(hv[0], hv[1]), pack2f(hv[2], hv[3]));
    if (t < 95) *(uint2*)&inb[nxt][sb][sc * 4] = sv;
    if (t == 95)
      *(float4*)&enc[(size_t)(bbase + n) * 128 + ju] = make_float4(hv[0], hv[1], hv[2], hv[3]);
    barrier_lds();
  }
}

// ---------------- prep: fold everything static into baseS + tables -------------
// baseS[b][s][k] = b1[k] + W1_enc.enc[b] + W1_emb.emb[b] + W1_exo.xfut[b,s]
//                  + W1_he.te(s)        (fp32 accumulate, stored fp16)
// block 1024: tproj[t][k] = W1_te(row k).te(t); cc[t]; packed w1y/w150 cols.
__global__ void k_prep_diff(const float* __restrict__ enc, const float* __restrict__ W1,
                            const float* __restrict__ b1, const float* __restrict__ xfut,
                            const float* __restrict__ temb, const int* __restrict__ tix,
                            __half* __restrict__ baseS, __half* __restrict__ tprojG,
                            float2* __restrict__ ccG, uint32_t* __restrict__ w1ypG,
                            uint32_t* __restrict__ w150pG) {
  const int k = threadIdx.x;
  const int b = blockIdx.x;
  if (b < 1024) {
    __shared__ float encL[128];
    __shared__ float embL[16];
    encL[k] = enc[b * 128 + k];
    if (k < 16) embL[k] = temb[tix[b] * 16 + k];
    __syncthreads();
    const float* wr = W1 + k * 184;
    float base0 = b1[k];
#pragma unroll 8
    for (int j = 0; j < 128; j++) base0 += wr[j] * encL[j];
#pragma unroll
    for (int i = 0; i < 16; i++) base0 += wr[134 + i] * embL[i];
    for (int s = 0; s < 8; s++) {
      float v = base0;
#pragma unroll
      for (int c = 0; c < 6; c++) v += wr[128 + c] * xfut[(b * 8 + s) * 6 + c];
#pragma unroll
      for (int i = 0; i < 16; i++) {
        float f = expf(-logf(10000.f) * (float)(i & 7) / 8.f);
        float a = (float)s * f;
        v += wr[168 + i] * ((i < 8) ? cosf(a) : sinf(a));
      }
      baseS[(b * 8 + s) * 128 + k] = __float2half_rn(v);
    }
  } else {
    const float* wr = W1 + k * 184;
    float wte[16];
#pragma unroll
    for (int i = 0; i < 16; i++) wte[i] = wr[152 + i];
    for (int tt = 0; tt < 100; tt++) {
      float sv = 0.f;
#pragma unroll
      for (int i = 0; i < 16; i++) {
        float f = expf(-logf(10000.f) * (float)(i & 7) / 8.f);
        float a = (float)tt * f;
        sv += wte[i] * ((i < 8) ? cosf(a) : sinf(a));
      }
      tprojG[tt * 128 + k] = __float2half_rn(sv);
    }
    if (k < 100) {
      float ab = 1.f, beta = 0.f;
      for (int i = 0; i <= k; i++) {
        beta = 1e-4f + (0.02f - 1e-4f) * (float)i / 99.f;
        ab *= (1.f - beta);
      }
      float cs, cd;
      if (k == 0) { cs = sqrtf(1.f - ab); cd = 1.f / (sqrtf(ab) + 1e-8f); }
      else { cs = beta / (sqrtf(1.f - ab) + 1e-8f); cd = 1.f / (sqrtf(1.f - beta) + 1e-8f); }
      ccG[k] = make_float2(cs, cd);
    }
    if (k < 64) {
      w1ypG[k]  = pack2f(W1[(2 * k) * 184 + 151], W1[(2 * k + 1) * 184 + 151]);
      w150pG[k] = pack2f(W1[(2 * k) * 184 + 150], W1[(2 * k + 1) * 184 + 150]);
    }
  }
}

// ---------------- AR diffusion: SINGLE WAVE, 2 chains x 16 batches, no barriers -
// lane l: m = l&15 (batch row & C-col n within tile), q = l>>4 (k-quarter).
// A-frag: A[m][k=f*32+q*8+j]; B-frag (W2): B[k][n=tile*16+m]; C: col n=l&15,
// row m=q*4+r. eps_m = rowsum16 over n-lanes + tile-sum in regs + shfl bcast.
__global__ __launch_bounds__(64, 1) void k_diff(
    const float* __restrict__ y0, const float* __restrict__ noise,
    const uint32_t* __restrict__ baseS, const uint32_t* __restrict__ tprojG,
    const float2* __restrict__ ccG, const uint32_t* __restrict__ w1ypG,
    const uint32_t* __restrict__ w150pG, const uint32_t* __restrict__ w2p,
    const float* __restrict__ b2, const float* __restrict__ W3,
    const float* __restrict__ b3, float* __restrict__ out) {
  __shared__ __align__(16) uint32_t tprojL[100 * 64];
  __shared__ float2 ccL[100];
  const int l = threadIdx.x;
  const int m = l & 15, q = l >> 4;
  const int bbase = blockIdx.x * 32;
  const int bA = bbase + m, bB = bbase + 16 + m;

  // stage tables
  for (int i = l; i < 1600; i += 64)
    ((uint4*)tprojL)[i] = ((const uint4*)tprojG)[i];
  for (int i = l; i < 100; i += 64) ccL[i] = ccG[i];

  // per-lane resident weights/tables
  uint4 w1yp4[4], w150p4[4];
#pragma unroll
  for (int f = 0; f < 4; f++) {
    w1yp4[f]  = ((const uint4*)w1ypG)[f * 4 + q];
    w150p4[f] = ((const uint4*)w150pG)[f * 4 + q];
  }
  uint4 Bf[8][4];
#pragma unroll
  for (int nt = 0; nt < 8; nt++)
#pragma unroll
    for (int f = 0; f < 4; f++)
      Bf[nt][f] = ((const uint4*)w2p)[(nt * 16 + m) * 16 + f * 4 + q];
  v4f b2s[8];
  float w3n[8];
#pragma unroll
  for (int nt = 0; nt < 8; nt++) {
    float bv = b2[nt * 16 + m];
    b2s[nt] = (v4f){bv, bv, bv, bv};
    w3n[nt] = W3[nt * 16 + m];
  }
  const float b3v = b3[0];
  const int srcLane = ((l >> 2) & 3) * 16 + 15;   // lane holding eps for m=l&15
  float pyA = y0[bA], pyB = y0[bB];
  __syncthreads();

  for (int s = 0; s < 8; s++) {
    // bph = baseS + w150*prev_y   (fp16 packed)
    uint32_t bphA[16], bphB[16];
    {
      uint32_t pyPA = cvtpk(pyA), pyPB = cvtpk(pyB);
#pragma unroll
      for (int f = 0; f < 4; f++) {
        uint4 ba = ((const uint4*)baseS)[(bA * 8 + s) * 16 + f * 4 + q];
        uint4 bb = ((const uint4*)baseS)[(bB * 8 + s) * 16 + f * 4 + q];
        bphA[f * 4 + 0] = pk_fma(w150p4[f].x, pyPA, ba.x);
        bphA[f * 4 + 1] = pk_fma(w150p4[f].y, pyPA, ba.y);
        bphA[f * 4 + 2] = pk_fma(w150p4[f].z, pyPA, ba.z);
        bphA[f * 4 + 3] = pk_fma(w150p4[f].w, pyPA, ba.w);
        bphB[f * 4 + 0] = pk_fma(w150p4[f].x, pyPB, bb.x);
        bphB[f * 4 + 1] = pk_fma(w150p4[f].y, pyPB, bb.y);
        bphB[f * 4 + 2] = pk_fma(w150p4[f].z, pyPB, bb.z);
        bphB[f * 4 + 3] = pk_fma(w150p4[f].w, pyPB, bb.w);
      }
    }
    float yA = noise[s * 1024 + bA];
    float yB = noise[s * 1024 + bB];

    // preload t=99 tproj and fold
    uint32_t btA[16], btB[16];
#pragma unroll
    for (int f = 0; f < 4; f++) {
      uint4 tv = *(const uint4*)&tprojL[99 * 64 + f * 16 + q * 4];
      btA[f * 4 + 0] = pk_add(bphA[f * 4 + 0], tv.x);
      btA[f * 4 + 1] = pk_add(bphA[f * 4 + 1], tv.y);
      btA[f * 4 + 2] = pk_add(bphA[f * 4 + 2], tv.z);
      btA[f * 4 + 3] = pk_add(bphA[f * 4 + 3], tv.w);
      btB[f * 4 + 0] = pk_add(bphB[f * 4 + 0], tv.x);
      btB[f * 4 + 1] = pk_add(bphB[f * 4 + 1], tv.y);
      btB[f * 4 + 2] = pk_add(bphB[f * 4 + 2], tv.z);
      btB[f * 4 + 3] = pk_add(bphB[f * 4 + 3], tv.w);
    }
    float2 ccv = ccL[99];

    for (int t = 99; t >= 0; t--) {
      uint32_t yPA = cvtpk(yA), yPB = cvtpk(yB);
      v4f accA[8], accB[8];
      // chain A: h1 frags + 32 MFMA (C init = b2 splat on f==0)
#pragma unroll
      for (int f = 0; f < 4; f++) {
        uint4 au;
        au.x = pk_relufma(w1yp4[f].x, yPA, btA[f * 4 + 0]);
        au.y = pk_relufma(w1yp4[f].y, yPA, btA[f * 4 + 1]);
        au.z = pk_relufma(w1yp4[f].z, yPA, btA[f * 4 + 2]);
        au.w = pk_relufma(w1yp4[f].w, yPA, btA[f * 4 + 3]);
        v8h A_ = __builtin_bit_cast(v8h, au);
#pragma unroll
        for (int nt = 0; nt < 8; nt++) {
          v4f c = (f == 0) ? b2s[nt] : accA[nt];
          accA[nt] = __builtin_amdgcn_mfma_f32_16x16x32_f16(
              A_, __builtin_bit_cast(v8h, Bf[nt][f]), c, 0, 0, 0);
        }
      }
      // chain B
#pragma unroll
      for (int f = 0; f < 4; f++) {
        uint4 au;
        au.x = pk_relufma(w1yp4[f].x, yPB, btB[f * 4 + 0]);
        au.y = pk_relufma(w1yp4[f].y, yPB, btB[f * 4 + 1]);
        au.z = pk_relufma(w1yp4[f].z, yPB, btB[f * 4 + 2]);
        au.w = pk_relufma(w1yp4[f].w, yPB, btB[f * 4 + 3]);
        v8h A_ = __builtin_bit_cast(v8h, au);
#pragma unroll
        for (int nt = 0; nt < 8; nt++) {
          v4f c = (f == 0) ? b2s[nt] : accB[nt];
          accB[nt] = __builtin_amdgcn_mfma_f32_16x16x32_f16(
              A_, __builtin_bit_cast(v8h, Bf[nt][f]), c, 0, 0, 0);
        }
      }
      // prefetch next tproj/cc + fold (overlaps MFMA pipe)
      const int tn = (t > 0) ? t - 1 : 0;
      uint32_t btnA[16], btnB[16];
#pragma unroll
      for (int f = 0; f < 4; f++) {
        uint4 tv = *(const uint4*)&tprojL[tn * 64 + f * 16 + q * 4];
        btnA[f * 4 + 0] = pk_add(bphA[f * 4 + 0], tv.x);
        btnA[f * 4 + 1] = pk_add(bphA[f * 4 + 1], tv.y);
        btnA[f * 4 + 2] = pk_add(bphA[f * 4 + 2], tv.z);
        btnA[f * 4 + 3] = pk_add(bphA[f * 4 + 3], tv.w);
        btnB[f * 4 + 0] = pk_add(bphB[f * 4 + 0], tv.x);
        btnB[f * 4 + 1] = pk_add(bphB[f * 4 + 1], tv.y);
        btnB[f * 4 + 2] = pk_add(bphB[f * 4 + 2], tv.z);
        btnB[f * 4 + 3] = pk_add(bphB[f * 4 + 3], tv.w);
      }
      float2 ccn = ccL[tn];
      // epilogue A: pr[r] = sum_nt w3*relu(acc), rowsum over n-lanes
      float prA[4], prB[4];
#pragma unroll
      for (int r = 0; r < 4; r++) {
        float pa = 0.f;
#pragma unroll
        for (int nt = 0; nt < 8; nt++) pa += w3n[nt] * fmaxf(accA[nt][r], 0.f);
        prA[r] = rowsum16(pa);
      }
#pragma unroll
      for (int r = 0; r < 4; r++) {
        float pb = 0.f;
#pragma unroll
        for (int nt = 0; nt < 8; nt++) pb += w3n[nt] * fmaxf(accB[nt][r], 0.f);
        prB[r] = rowsum16(pb);
      }
      // broadcast eps_m to all lanes (in-wave shfl; r-select by l&3)
      float a0 = __shfl(prA[0], srcLane, 64), a1 = __shfl(prA[1], srcLane, 64);
      float a2 = __shfl(prA[2], srcLane, 64), a3 = __shfl(prA[3], srcLane, 64);
      float e0 = __shfl(prB[0], srcLane, 64), e1 = __shfl(prB[1], srcLane, 64);
      float e2 = __shfl(prB[2], srcLane, 64), e3 = __shfl(prB[3], srcLane, 64);
      float epsA = (l & 1) ? ((l & 2) ? a3 : a1) : ((l & 2) ? a2 : a0);
      float epsB = (l & 1) ? ((l & 2) ? e3 : e1) : ((l & 2) ? e2 : e0);
      epsA += b3v;
      epsB += b3v;
      yA = (yA - ccv.x * epsA) * ccv.y;
      yB = (yB - ccv.x * epsB) * ccv.y;
      ccv = ccn;
#pragma unroll
      for (int pi = 0; pi < 16; pi++) { btA[pi] = btnA[pi]; btB[pi] = btnB[pi]; }
    }
    if (l < 16) out[(bbase + l) * 8 + s] = yA;
    else if (l < 32) out[(bbase + l) * 8 + s] = yB;
    pyA = yA;
    pyB = yB;
  }
}

// ---------------------------------------------------------------------------
extern "C" void kernel_launch(void* const* d_in, const int* in_sizes, int n_in,
                              void* d_out, int out_size, void* d_ws, size_t ws_size,
                              hipStream_t stream) {
  const float* x_hist    = (const float*)d_in[0];
  const float* x_future  = (const float*)d_in[1];
  const float* y0        = (const float*)d_in[2];
  const int*   turb_idx  = (const int*)d_in[3];
  const float* init_noise = (const float*)d_in[5];
  const float* turb_emb  = (const float*)d_in[6];
  const float* W_ih0     = (const float*)d_in[7];
  const float* W_hh0     = (const float*)d_in[8];
  const float* b_ih0     = (const float*)d_in[9];
  const float* b_hh0     = (const float*)d_in[10];
  const float* W_ih1     = (const float*)d_in[11];
  const float* W_hh1     = (const float*)d_in[12];
  const float* b_ih1     = (const float*)d_in[13];
  const float* b_hh1     = (const float*)d_in[14];
  const float* W1        = (const float*)d_in[15];
  const float* b1        = (const float*)d_in[16];
  const float* W2        = (const float*)d_in[17];
  const float* b2        = (const float*)d_in[18];
  const float* W3        = (const float*)d_in[19];
  const float* b3        = (const float*)d_in[20];

  char* ws = (char*)d_ws;
  uint32_t* xh16 = (uint32_t*)(ws + OFF_XH);
  uint32_t* w0p  = (uint32_t*)(ws + OFF_W0);
  float*    bs0  = (float*)(ws + OFF_BS0);
  uint32_t* w1p  = (uint32_t*)(ws + OFF_W1L);
  float*    bs1  = (float*)(ws + OFF_BS1);
  uint32_t* w2p  = (uint32_t*)(ws + OFF_W2P);
  float*    encf = (float*)(ws + OFF_ENC);
  __half*   ys0h = (__half*)(ws + OFF_YS0);
  // aliased onto the xh16 region (dead after k_lstm0):
  __half*   baseS  = (__half*)(ws + OFF_BASES);
  __half*   tprojG = (__half*)(ws + OFF_TPROJ);
  float2*   ccG    = (float2*)(ws + OFF_CC);
  uint32_t* w1ypG  = (uint32_t*)(ws + OFF_W1YP);
  uint32_t* w150pG = (uint32_t*)(ws + OFF_W150P);

  k_prep_xh<<<4608, 256, 0, stream>>>(x_hist, turb_idx, turb_emb, xh16);
  k_prep_w<<<452, 256, 0, stream>>>(W_ih0, W_hh0, b_ih0, b_hh0,
                                    W_ih1, W_hh1, b_ih1, b_hh1,
                                    W2, w0p, w1p, w2p, bs0, bs1);
  k_lstm0<<<64, 512, 0, stream>>>(xh16, w0p, bs0, ys0h);
  k_lstm1<<<64, 512, 0, stream>>>((const uint32_t*)ys0h, w1p, bs1, encf);
  k_prep_diff<<<1025, 128, 0, stream>>>(encf, W1, b1, x_future, turb_emb, turb_idx,
                                        baseS, tprojG, ccG, w1ypG, w150pG);
  k_diff<<<32, 64, 0, stream>>>(y0, init_noise, (const uint32_t*)baseS,
                                (const uint32_t*)tprojG, ccG, w1ypG, w150pG,
                                w2p, b2, W3, b3, (float*)d_out);
}

// Round 8
// 834.087 us; speedup vs baseline: 1.7139x; 1.7139x over previous
//
#include <hip/hip_runtime.h>
#include <hip/hip_fp16.h>
#include <stdint.h>

// ---------------------------------------------------------------------------
// Seq2SeqARDiffusion on MI355X.
//   k_prep_xh  : pack [x_hist|emb] fp16 inputs for LSTM0
//   k_prep_w   : pack LSTM weights into MFMA A-fragment order (+ W2, bias sums)
//   k_lstm0    : persistent MFMA LSTM layer 0, 64 WGs x 512 thr, 16 batch/WG
//   k_lstm1    : persistent MFMA LSTM layer 1 -> enc_out
//   k_prep_diff: fold enc/emb/exo/hproj/b1 into baseS[b][s][k] (f32 acc),
//                tproj/cc/w1y/w150 tables  (aliases dead xh16 region)
//   k_diff     : 64 WGs x 128 thr (2 waves), 1 chain of 16 batches/WG,
//                n=128 split 4 n-tiles/wave (16 MFMA/wave/step), 2-wave
//                barrier + 2-way partial; b2 in MFMA C; direct tproj add.
// ---------------------------------------------------------------------------

typedef __attribute__((ext_vector_type(2))) _Float16 half2_t;
typedef __attribute__((ext_vector_type(8))) _Float16 v8h;
typedef __attribute__((ext_vector_type(4))) float v4f;

#define DEV __device__ __forceinline__

// Barrier with LDS-only drain (skips vmcnt(0) drain of __syncthreads).
DEV void barrier_lds() {
  asm volatile("s_waitcnt lgkmcnt(0)\ns_barrier" ::: "memory");
}

DEV uint32_t pack2f(float a, float b) {
  __half ha = __float2half_rn(a), hb = __float2half_rn(b);
  return (uint32_t)__half_as_ushort(ha) | ((uint32_t)__half_as_ushort(hb) << 16);
}

DEV float fast_ex2(float x) {
#if __has_builtin(__builtin_amdgcn_exp2f)
  return __builtin_amdgcn_exp2f(x);
#else
  return exp2f(x);
#endif
}
DEV float fast_rcp(float x) {
#if __has_builtin(__builtin_amdgcn_rcpf)
  return __builtin_amdgcn_rcpf(x);
#else
  return 1.f / x;
#endif
}
DEV float sigm(float x) { return fast_rcp(1.f + fast_ex2(-1.4426950408889634f * x)); }
DEV float tanh_f(float x) {
  return 2.f * fast_rcp(1.f + fast_ex2(-2.8853900817779268f * x)) - 1.f;
}

DEV uint32_t pk_add(uint32_t a, uint32_t b) {
  return __builtin_bit_cast(uint32_t,
      __builtin_bit_cast(half2_t, a) + __builtin_bit_cast(half2_t, b));
}

// w*y + b, packed fp16
DEV uint32_t pk_fma(uint32_t w, uint32_t y, uint32_t b) {
  return __builtin_bit_cast(uint32_t,
      __builtin_bit_cast(half2_t, w) * __builtin_bit_cast(half2_t, y) +
      __builtin_bit_cast(half2_t, b));
}

// relu(w*y + b), packed fp16
DEV uint32_t pk_relufma(uint32_t w, uint32_t y, uint32_t b) {
  half2_t r = __builtin_bit_cast(half2_t, w) * __builtin_bit_cast(half2_t, y) +
              __builtin_bit_cast(half2_t, b);
  half2_t z = {(_Float16)0.f, (_Float16)0.f};
#if __has_builtin(__builtin_elementwise_max)
  r = __builtin_elementwise_max(r, z);
#else
  uint32_t u = __builtin_bit_cast(uint32_t, r);
  uint32_t mask = ((u >> 15) & 1u) * 0xFFFFu | ((u >> 31) & 1u) * 0xFFFF0000u;
  r = __builtin_bit_cast(half2_t, u & ~mask);
#endif
  return __builtin_bit_cast(uint32_t, r);
}

DEV uint32_t cvtpk(float y) {
#if __has_builtin(__builtin_amdgcn_cvt_pkrtz)
  return __builtin_bit_cast(uint32_t, __builtin_amdgcn_cvt_pkrtz(y, y));
#else
  return pack2f(y, y);
#endif
}

// sum within each 16-lane row; lane (l&15)==15 holds the row sum
DEV float rowsum16(float v) {
  int x;
  x = __builtin_amdgcn_update_dpp(0, __builtin_bit_cast(int, v), 0x111, 0xf, 0xf, true);
  v += __builtin_bit_cast(float, x);
  x = __builtin_amdgcn_update_dpp(0, __builtin_bit_cast(int, v), 0x112, 0xf, 0xf, true);
  v += __builtin_bit_cast(float, x);
  x = __builtin_amdgcn_update_dpp(0, __builtin_bit_cast(int, v), 0x114, 0xf, 0xf, true);
  v += __builtin_bit_cast(float, x);
  x = __builtin_amdgcn_update_dpp(0, __builtin_bit_cast(int, v), 0x118, 0xf, 0xf, true);
  v += __builtin_bit_cast(float, x);
  return v;
}

// ---------------- workspace layout (bytes) ----------------
static constexpr size_t OFF_XH  = 0;                 // 96*1024*12 u32 = 4,718,592
static constexpr size_t OFF_W0  = 4718592;           // w0A 40960 u32 = 163,840
static constexpr size_t OFF_BS0 = 4882432;           // 512 f32
static constexpr size_t OFF_W1L = 4884480;           // w1A 65536 u32 = 262,144
static constexpr size_t OFF_BS1 = 5146624;           // 512 f32
static constexpr size_t OFF_W2P = 5148672;           // 128*64 u32 = 32,768
static constexpr size_t OFF_ENC = 5181440;           // 1024*128 f32 = 524,288
static constexpr size_t OFF_YS0 = 5705728;           // 96*1024*128 half = 25,165,824
// aliased into the dead xh16 region (xh16 only live until k_lstm0):
static constexpr size_t OFF_BASES = 0;               // half[1024*8*128] = 2,097,152
static constexpr size_t OFF_TPROJ = 2097152;         // half[100*128] = 25,600
static constexpr size_t OFF_CC    = 2122752;         // float2[100] = 800
static constexpr size_t OFF_W1YP  = 2123584;         // u32[64]
static constexpr size_t OFF_W150P = 2123840;         // u32[64]

// ---------------- prep: pack [x_hist | emb] as fp16 pairs ----------------
__global__ void k_prep_xh(const float* __restrict__ xh, const int* __restrict__ tix,
                          const float* __restrict__ temb, uint32_t* __restrict__ out) {
  int idx = blockIdx.x * 256 + threadIdx.x;          // 96*1024*12 total
  if (idx >= 96 * 1024 * 12) return;
  int m = idx % 12;
  int tb = idx / 12;
  int b = tb & 1023, t = tb >> 10;
  int k0 = 2 * m, k1 = k0 + 1;
  float v0 = (k0 < 8) ? xh[(b * 96 + t) * 8 + k0] : temb[tix[b] * 16 + (k0 - 8)];
  float v1 = (k1 < 8) ? xh[(b * 96 + t) * 8 + k1] : temb[tix[b] * 16 + (k1 - 8)];
  out[idx] = pack2f(v0, v1);
}

// ---------------- prep: pack LSTM/W2 weights ----------------
__global__ void k_prep_w(const float* __restrict__ Wih0, const float* __restrict__ Whh0,
                         const float* __restrict__ bih0, const float* __restrict__ bhh0,
                         const float* __restrict__ Wih1, const float* __restrict__ Whh1,
                         const float* __restrict__ bih1, const float* __restrict__ bhh1,
                         const float* __restrict__ W2,
                         uint32_t* __restrict__ w0p, uint32_t* __restrict__ w1p,
                         uint32_t* __restrict__ w2p, float* __restrict__ bs0,
                         float* __restrict__ bs1) {
  int idx = blockIdx.x * 256 + threadIdx.x;
  if (idx < 40960) {                       // w0A: NF=5, K=160 ([x24|h128|pad8])
    int w = idx / 5120;
    int r = idx % 5120;
    int T = r / 1280; r %= 1280;
    int f = r / 256;  r %= 256;
    int l = r >> 2, c = r & 3;
    int m = l & 15, qf = l >> 4;
    int g = (m & 3) * 128 + w * 16 + (m >> 2) * 4 + T;
    int k0 = f * 32 + qf * 8 + 2 * c, k1 = k0 + 1;
    float a = (k0 < 24) ? Wih0[g * 24 + k0] : ((k0 < 152) ? Whh0[g * 128 + k0 - 24] : 0.f);
    float b = (k1 < 24) ? Wih0[g * 24 + k1] : ((k1 < 152) ? Whh0[g * 128 + k1 - 24] : 0.f);
    w0p[idx] = pack2f(a, b);
  } else if (idx < 106496) {               // w1A: NF=8, K=256 ([ys0 128|h128])
    int i = idx - 40960;
    int w = i / 8192;
    int r = i % 8192;
    int T = r / 2048; r %= 2048;
    int f = r / 256;  r %= 256;
    int l = r >> 2, c = r & 3;
    int m = l & 15, qf = l >> 4;
    int g = (m & 3) * 128 + w * 16 + (m >> 2) * 4 + T;
    int k0 = f * 32 + qf * 8 + 2 * c, k1 = k0 + 1;
    float a = (k0 < 128) ? Wih1[g * 128 + k0] : Whh1[g * 128 + k0 - 128];
    float b = (k1 < 128) ? Wih1[g * 128 + k1] : Whh1[g * 128 + k1 - 128];
    w1p[i] = pack2f(a, b);
  } else if (idx < 114688) {               // W2: 128 x 64 u32 (row-major pairs)
    int i = idx - 106496;
    w2p[i] = pack2f(W2[2 * i], W2[2 * i + 1]);
  } else if (idx < 115200) {
    int i = idx - 114688;
    bs0[i] = bih0[i] + bhh0[i];
  } else if (idx < 115712) {
    int i = idx - 115200;
    bs1[i] = bih1[i] + bhh1[i];
  }
}

// ---------------- LSTM layer 0 (MFMA; 16 batch/WG, 64 WGs x 512) ----------------
__global__ __launch_bounds__(512, 2) void k_lstm0(const uint32_t* __restrict__ xh16,
                                                  const uint32_t* __restrict__ w0A,
                                                  const float* __restrict__ bs0,
                                                  __half* __restrict__ ys0) {
  __shared__ __align__(16) __half inb[2][16][160];
  const int tid = threadIdx.x;
  const int w = tid >> 6, l = tid & 63;
  const int n = l & 15, ql = l >> 4;
  const int ju = w * 16 + ql * 4;
  const int bbase = blockIdx.x * 16;

  uint4 Af[4][5];
#pragma unroll
  for (int T = 0; T < 4; T++)
#pragma unroll
    for (int f = 0; f < 5; f++)
      Af[T][f] = ((const uint4*)w0A)[((w * 4 + T) * 5 + f) * 64 + l];
  float bias[4][4];
#pragma unroll
  for (int T = 0; T < 4; T++)
#pragma unroll
    for (int r = 0; r < 4; r++) bias[T][r] = bs0[r * 128 + ju + T];

  for (int i = tid; i < 2560; i += 512) ((uint32_t*)inb)[i] = 0u;
  __syncthreads();
  if (tid < 192) {
    int b = tid / 12, m = tid % 12;
    ((uint32_t*)&inb[0][b][0])[m] = xh16[(0 * 1024 + bbase + b) * 12 + m];
  }
  float cst[4] = {0.f, 0.f, 0.f, 0.f};
  __syncthreads();

  for (int t = 0; t < 96; t++) {
    const int cur = t & 1, nxt = cur ^ 1;
    uint32_t sx = 0;
    int sb = 0, sm = 0;
    if (t < 95 && tid < 192) {
      sb = tid / 12; sm = tid % 12;
      sx = xh16[((t + 1) * 1024 + bbase + sb) * 12 + sm];
    }
    v4f acc[4];
#pragma unroll
    for (int T = 0; T < 4; T++) acc[T] = (v4f){0.f, 0.f, 0.f, 0.f};
#pragma unroll
    for (int f = 0; f < 5; f++) {
      uint4 bu = *(const uint4*)&inb[cur][n][f * 32 + ql * 8];
      v8h Bv = __builtin_bit_cast(v8h, bu);
#pragma unroll
      for (int T = 0; T < 4; T++)
        acc[T] = __builtin_amdgcn_mfma_f32_16x16x32_f16(
            __builtin_bit_cast(v8h, Af[T][f]), Bv, acc[T], 0, 0, 0);
    }
    float hv[4];
#pragma unroll
    for (int T = 0; T < 4; T++) {
      float gi = acc[T][0] + bias[T][0];
      float gf = acc[T][1] + bias[T][1];
      float gg = acc[T][2] + bias[T][2];
      float go = acc[T][3] + bias[T][3];
      float c = sigm(gf) * cst[T] + sigm(gi) * tanh_f(gg);
      cst[T] = c;
      hv[T] = sigm(go) * tanh_f(c);
    }
    uint32_t h01 = pack2f(hv[0], hv[1]), h23 = pack2f(hv[2], hv[3]);
    *(uint2*)&inb[nxt][n][24 + ju] = make_uint2(h01, h23);
    *(uint2*)((__half*)ys0 + (size_t)(t * 1024 + bbase + n) * 128 + ju) = make_uint2(h01, h23);
    if (t < 95 && tid < 192) ((uint32_t*)&inb[nxt][sb][0])[sm] = sx;
    barrier_lds();
  }
}

// ---------------- LSTM layer 1 (MFMA; 16 batch/WG, 64 WGs x 512) ----------------
__global__ __launch_bounds__(512, 2) void k_lstm1(const uint32_t* __restrict__ ys0u,
                                                  const uint32_t* __restrict__ w1A,
                                                  const float* __restrict__ bs1,
                                                  float* __restrict__ enc) {
  __shared__ __align__(16) __half inb[2][16][264];
  const int tid = threadIdx.x;
  const int w = tid >> 6, l = tid & 63;
  const int n = l & 15, ql = l >> 4;
  const int ju = w * 16 + ql * 4;
  const int bbase = blockIdx.x * 16;
  const int sb = tid >> 5, sc = tid & 31;

  uint4 Af[4][8];
#pragma unroll
  for (int T = 0; T < 4; T++)
#pragma unroll
    for (int f = 0; f < 8; f++)
      Af[T][f] = ((const uint4*)w1A)[((w * 4 + T) * 8 + f) * 64 + l];
  float bias[4][4];
#pragma unroll
  for (int T = 0; T < 4; T++)
#pragma unroll
    for (int r = 0; r < 4; r++) bias[T][r] = bs1[r * 128 + ju + T];

  for (int i = tid; i < 4224; i += 512) ((uint32_t*)inb)[i] = 0u;
  __syncthreads();
  {
    uint2 v = ((const uint2*)ys0u)[(size_t)(0 * 1024 + bbase + sb) * 32 + sc];
    *(uint2*)&inb[0][sb][sc * 4] = v;
  }
  float cst[4] = {0.f, 0.f, 0.f, 0.f};
  __syncthreads();

  for (int t = 0; t < 96; t++) {
    const int cur = t & 1, nxt = cur ^ 1;
    uint2 sv = make_uint2(0u, 0u);
    if (t < 95)
      sv = ((const uint2*)ys0u)[(size_t)((t + 1) * 1024 + bbase + sb) * 32 + sc];
    v4f acc[4];
#pragma unroll
    for (int T = 0; T < 4; T++) acc[T] = (v4f){0.f, 0.f, 0.f, 0.f};
#pragma unroll
    for (int f = 0; f < 8; f++) {
      uint4 bu = *(const uint4*)&inb[cur][n][f * 32 + ql * 8];
      v8h Bv = __builtin_bit_cast(v8h, bu);
#pragma unroll
      for (int T = 0; T < 4; T++)
        acc[T] = __builtin_amdgcn_mfma_f32_16x16x32_f16(
            __builtin_bit_cast(v8h, Af[T][f]), Bv, acc[T], 0, 0, 0);
    }
    float hv[4];
#pragma unroll
    for (int T = 0; T < 4; T++) {
      float gi = acc[T][0] + bias[T][0];
      float gf = acc[T][1] + bias[T][1];
      float gg = acc[T][2] + bias[T][2];
      float go = acc[T][3] + bias[T][3];
      float c = sigm(gf) * cst[T] + sigm(gi) * tanh_f(gg);
      cst[T] = c;
      hv[T] = sigm(go) * tanh_f(c);
    }
    *(uint2*)&inb[nxt][n][128 + ju] = make_uint2(pack2f(hv[0], hv[1]), pack2f(hv[2], hv[3]));
    if (t < 95) *(uint2*)&inb[nxt][sb][sc * 4] = sv;
    if (t == 95)
      *(float4*)&enc[(size_t)(bbase + n) * 128 + ju] = make_float4(hv[0], hv[1], hv[2], hv[3]);
    barrier_lds();
  }
}

// ---------------- prep: fold everything static into baseS + tables -------------
// baseS[b][s][k] = b1[k] + W1_enc.enc[b] + W1_emb.emb[b] + W1_exo.xfut[b,s]
//                  + W1_he.te(s)        (fp32 accumulate, stored fp16)
// block 1024: tproj[t][k] = W1_te(row k).te(t); cc[t]; packed w1y/w150 cols.
__global__ void k_prep_diff(const float* __restrict__ enc, const float* __restrict__ W1,
                            const float* __restrict__ b1, const float* __restrict__ xfut,
                            const float* __restrict__ temb, const int* __restrict__ tix,
                            __half* __restrict__ baseS, __half* __restrict__ tprojG,
                            float2* __restrict__ ccG, uint32_t* __restrict__ w1ypG,
                            uint32_t* __restrict__ w150pG) {
  const int k = threadIdx.x;
  const int b = blockIdx.x;
  if (b < 1024) {
    __shared__ float encL[128];
    __shared__ float embL[16];
    encL[k] = enc[b * 128 + k];
    if (k < 16) embL[k] = temb[tix[b] * 16 + k];
    __syncthreads();
    const float* wr = W1 + k * 184;
    float base0 = b1[k];
#pragma unroll 8
    for (int j = 0; j < 128; j++) base0 += wr[j] * encL[j];
#pragma unroll
    for (int i = 0; i < 16; i++) base0 += wr[134 + i] * embL[i];
    for (int s = 0; s < 8; s++) {
      float v = base0;
#pragma unroll
      for (int c = 0; c < 6; c++) v += wr[128 + c] * xfut[(b * 8 + s) * 6 + c];
#pragma unroll
      for (int i = 0; i < 16; i++) {
        float f = expf(-logf(10000.f) * (float)(i & 7) / 8.f);
        float a = (float)s * f;
        v += wr[168 + i] * ((i < 8) ? cosf(a) : sinf(a));
      }
      baseS[(b * 8 + s) * 128 + k] = __float2half_rn(v);
    }
  } else {
    const float* wr = W1 + k * 184;
    float wte[16];
#pragma unroll
    for (int i = 0; i < 16; i++) wte[i] = wr[152 + i];
    for (int tt = 0; tt < 100; tt++) {
      float sv = 0.f;
#pragma unroll
      for (int i = 0; i < 16; i++) {
        float f = expf(-logf(10000.f) * (float)(i & 7) / 8.f);
        float a = (float)tt * f;
        sv += wte[i] * ((i < 8) ? cosf(a) : sinf(a));
      }
      tprojG[tt * 128 + k] = __float2half_rn(sv);
    }
    if (k < 100) {
      float ab = 1.f, beta = 0.f;
      for (int i = 0; i <= k; i++) {
        beta = 1e-4f + (0.02f - 1e-4f) * (float)i / 99.f;
        ab *= (1.f - beta);
      }
      float cs, cd;
      if (k == 0) { cs = sqrtf(1.f - ab); cd = 1.f / (sqrtf(ab) + 1e-8f); }
      else { cs = beta / (sqrtf(1.f - ab) + 1e-8f); cd = 1.f / (sqrtf(1.f - beta) + 1e-8f); }
      ccG[k] = make_float2(cs, cd);
    }
    if (k < 64) {
      w1ypG[k]  = pack2f(W1[(2 * k) * 184 + 151], W1[(2 * k + 1) * 184 + 151]);
      w150pG[k] = pack2f(W1[(2 * k) * 184 + 150], W1[(2 * k + 1) * 184 + 150]);
    }
  }
}

// ---------------- AR diffusion: 2 waves/WG, 16 batches/WG, 64 WGs --------------
// lane l: m = l&15 (batch & C-col within tile), q = l>>4 (k-quarter).
// wave w handles n-tiles nt = w*4+j, j in 0..3 (n = nt*16 + m).
// A-frag: A[m][k=f*32+q*8+..]; C: col n, row m=q*4+r. eps: per-wave rowsum16
// over its 4 n-tiles -> partL[buf][w][m] -> 2-wave barrier -> 2-way sum.
__global__ __launch_bounds__(128, 1) void k_diff(
    const float* __restrict__ y0, const float* __restrict__ noise,
    const uint32_t* __restrict__ baseS, const uint32_t* __restrict__ tprojG,
    const float2* __restrict__ ccG, const uint32_t* __restrict__ w1ypG,
    const uint32_t* __restrict__ w150pG, const uint32_t* __restrict__ w2p,
    const float* __restrict__ b2, const float* __restrict__ W3,
    const float* __restrict__ b3, float* __restrict__ out) {
  __shared__ __align__(16) uint32_t tprojL[100 * 64];
  __shared__ float2 ccL[100];
  __shared__ __align__(16) float partL[2][2][16];   // [buf][wave][m]
  const int tid = threadIdx.x;
  const int w = tid >> 6, l = tid & 63;
  const int m = l & 15, q = l >> 4;
  const int bbase = blockIdx.x * 16;
  const int b = bbase + m;

  // stage tables
  for (int i = tid; i < 1600; i += 128)
    ((uint4*)tprojL)[i] = ((const uint4*)tprojG)[i];
  for (int i = tid; i < 100; i += 128) ccL[i] = ccG[i];

  // per-lane resident weights
  uint4 w1yp4[4], w150p4[4];
#pragma unroll
  for (int f = 0; f < 4; f++) {
    w1yp4[f]  = ((const uint4*)w1ypG)[f * 4 + q];
    w150p4[f] = ((const uint4*)w150pG)[f * 4 + q];
  }
  uint4 Bf[4][4];
  const uint4* w2u4 = (const uint4*)w2p;
#pragma unroll
  for (int j = 0; j < 4; j++)
#pragma unroll
    for (int f = 0; f < 4; f++)
      Bf[j][f] = w2u4[((w * 4 + j) * 16 + m) * 16 + f * 4 + q];
  v4f b2s[4];
  float w3n[4];
#pragma unroll
  for (int j = 0; j < 4; j++) {
    float bv = b2[(w * 4 + j) * 16 + m];
    b2s[j] = (v4f){bv, bv, bv, bv};
    w3n[j] = W3[(w * 4 + j) * 16 + m];
  }
  const float b3v = b3[0];
  float py = y0[b];
  __syncthreads();

  int buf = 0;
  for (int s = 0; s < 8; s++) {
    // bph = baseS(b,s) + w150*prev_y  (packed fp16, once per AR step)
    uint32_t bph[16];
    {
      uint32_t pyP = cvtpk(py);
#pragma unroll
      for (int f = 0; f < 4; f++) {
        uint4 ba = ((const uint4*)baseS)[(b * 8 + s) * 16 + f * 4 + q];
        bph[f * 4 + 0] = pk_fma(w150p4[f].x, pyP, ba.x);
        bph[f * 4 + 1] = pk_fma(w150p4[f].y, pyP, ba.y);
        bph[f * 4 + 2] = pk_fma(w150p4[f].z, pyP, ba.z);
        bph[f * 4 + 3] = pk_fma(w150p4[f].w, pyP, ba.w);
      }
    }
    float y = noise[s * 1024 + b];

    for (int t = 99; t >= 0; t--) {
      uint32_t yP = cvtpk(y);
      v4f acc[4];
#pragma unroll
      for (int f = 0; f < 4; f++) {
        uint4 tv = *(const uint4*)&tprojL[t * 64 + f * 16 + q * 4];
        uint4 au;
        au.x = pk_relufma(w1yp4[f].x, yP, pk_add(bph[f * 4 + 0], tv.x));
        au.y = pk_relufma(w1yp4[f].y, yP, pk_add(bph[f * 4 + 1], tv.y));
        au.z = pk_relufma(w1yp4[f].z, yP, pk_add(bph[f * 4 + 2], tv.z));
        au.w = pk_relufma(w1yp4[f].w, yP, pk_add(bph[f * 4 + 3], tv.w));
        v8h A_ = __builtin_bit_cast(v8h, au);
#pragma unroll
        for (int j = 0; j < 4; j++) {
          v4f c = (f == 0) ? b2s[j] : acc[j];
          acc[j] = __builtin_amdgcn_mfma_f32_16x16x32_f16(
              A_, __builtin_bit_cast(v8h, Bf[j][f]), c, 0, 0, 0);
        }
      }
      // epilogue: pr[r] = sum_j w3*relu(acc[j][r]) reduced over 16 n-lanes
      float pr[4];
#pragma unroll
      for (int r = 0; r < 4; r++) {
        float pa = w3n[0] * fmaxf(acc[0][r], 0.f) + w3n[1] * fmaxf(acc[1][r], 0.f) +
                   w3n[2] * fmaxf(acc[2][r], 0.f) + w3n[3] * fmaxf(acc[3][r], 0.f);
        pr[r] = rowsum16(pa);
      }
      if ((l & 15) == 15)
        *(float4*)&partL[buf][w][q * 4] = make_float4(pr[0], pr[1], pr[2], pr[3]);
      float2 ccv = ccL[t];
      barrier_lds();
      float eps = b3v + partL[buf][0][m] + partL[buf][1][m];
      y = (y - ccv.x * eps) * ccv.y;
      buf ^= 1;
    }
    if (w == 0 && l < 16) out[(bbase + l) * 8 + s] = y;
    py = y;
  }
}

// ---------------------------------------------------------------------------
extern "C" void kernel_launch(void* const* d_in, const int* in_sizes, int n_in,
                              void* d_out, int out_size, void* d_ws, size_t ws_size,
                              hipStream_t stream) {
  const float* x_hist    = (const float*)d_in[0];
  const float* x_future  = (const float*)d_in[1];
  const float* y0        = (const float*)d_in[2];
  const int*   turb_idx  = (const int*)d_in[3];
  const float* init_noise = (const float*)d_in[5];
  const float* turb_emb  = (const float*)d_in[6];
  const float* W_ih0     = (const float*)d_in[7];
  const float* W_hh0     = (const float*)d_in[8];
  const float* b_ih0     = (const float*)d_in[9];
  const float* b_hh0     = (const float*)d_in[10];
  const float* W_ih1     = (const float*)d_in[11];
  const float* W_hh1     = (const float*)d_in[12];
  const float* b_ih1     = (const float*)d_in[13];
  const float* b_hh1     = (const float*)d_in[14];
  const float* W1        = (const float*)d_in[15];
  const float* b1        = (const float*)d_in[16];
  const float* W2        = (const float*)d_in[17];
  const float* b2        = (const float*)d_in[18];
  const float* W3        = (const float*)d_in[19];
  const float* b3        = (const float*)d_in[20];

  char* ws = (char*)d_ws;
  uint32_t* xh16 = (uint32_t*)(ws + OFF_XH);
  uint32_t* w0p  = (uint32_t*)(ws + OFF_W0);
  float*    bs0  = (float*)(ws + OFF_BS0);
  uint32_t* w1p  = (uint32_t*)(ws + OFF_W1L);
  float*    bs1  = (float*)(ws + OFF_BS1);
  uint32_t* w2p  = (uint32_t*)(ws + OFF_W2P);
  float*    encf = (float*)(ws + OFF_ENC);
  __half*   ys0h = (__half*)(ws + OFF_YS0);
  // aliased onto the xh16 region (dead after k_lstm0):
  __half*   baseS  = (__half*)(ws + OFF_BASES);
  __half*   tprojG = (__half*)(ws + OFF_TPROJ);
  float2*   ccG    = (float2*)(ws + OFF_CC);
  uint32_t* w1ypG  = (uint32_t*)(ws + OFF_W1YP);
  uint32_t* w150pG = (uint32_t*)(ws + OFF_W150P);

  k_prep_xh<<<4608, 256, 0, stream>>>(x_hist, turb_idx, turb_emb, xh16);
  k_prep_w<<<452, 256, 0, stream>>>(W_ih0, W_hh0, b_ih0, b_hh0,
                                    W_ih1, W_hh1, b_ih1, b_hh1,
                                    W2, w0p, w1p, w2p, bs0, bs1);
  k_lstm0<<<64, 512, 0, stream>>>(xh16, w0p, bs0, ys0h);
  k_lstm1<<<64, 512, 0, stream>>>((const uint32_t*)ys0h, w1p, bs1, encf);
  k_prep_diff<<<1025, 128, 0, stream>>>(encf, W1, b1, x_future, turb_emb, turb_idx,
                                        baseS, tprojG, ccG, w1ypG, w150pG);
  k_diff<<<64, 128, 0, stream>>>(y0, init_noise, (const uint32_t*)baseS,
                                 (const uint32_t*)tprojG, ccG, w1ypG, w150pG,
                                 w2p, b2, W3, b3, (float*)d_out);
}

// Round 9
// 689.260 us; speedup vs baseline: 2.0740x; 1.2101x over previous
//
#include <hip/hip_runtime.h>
#include <hip/hip_fp16.h>
#include <stdint.h>

// ---------------------------------------------------------------------------
// Seq2SeqARDiffusion on MI355X.
//   k_prep_xh  : pack [x_hist|emb] fp16 inputs for LSTM0
//   k_prep_w   : pack LSTM weights into MFMA A-fragment order (+ W2, bias sums)
//   k_lstm0    : persistent MFMA LSTM layer 0, 64 WGs x 512 thr, 16 batch/WG
//   k_lstm1    : persistent MFMA LSTM layer 1 -> enc_out
//   k_prep_diff: fold enc/emb/exo/hproj/b1 into baseS[b][s][k] (f32 acc),
//                tproj/cc/w1y/w150 tables (LDS-hoisted sin/cos)
//   k_diff     : 64 WGs x 128 thr (2 waves), 16 batches/WG. Round 9:
//                OPERAND-SWAPPED GEMV (C = [hidden][batch]) -> local W3 dot
//                + shfl_xor reduce, 1-float LDS exchange; tproj/cc register
//                prefetch before the barrier; bt ping-pong (2x unroll).
// ---------------------------------------------------------------------------

typedef __attribute__((ext_vector_type(2))) _Float16 half2_t;
typedef __attribute__((ext_vector_type(8))) _Float16 v8h;
typedef __attribute__((ext_vector_type(4))) float v4f;

#define DEV __device__ __forceinline__

// Barrier with LDS-only drain (skips vmcnt(0) drain of __syncthreads).
DEV void barrier_lds() {
  asm volatile("s_waitcnt lgkmcnt(0)\ns_barrier" ::: "memory");
}

DEV uint32_t pack2f(float a, float b) {
  __half ha = __float2half_rn(a), hb = __float2half_rn(b);
  return (uint32_t)__half_as_ushort(ha) | ((uint32_t)__half_as_ushort(hb) << 16);
}

DEV float fast_ex2(float x) {
#if __has_builtin(__builtin_amdgcn_exp2f)
  return __builtin_amdgcn_exp2f(x);
#else
  return exp2f(x);
#endif
}
DEV float fast_rcp(float x) {
#if __has_builtin(__builtin_amdgcn_rcpf)
  return __builtin_amdgcn_rcpf(x);
#else
  return 1.f / x;
#endif
}
DEV float sigm(float x) { return fast_rcp(1.f + fast_ex2(-1.4426950408889634f * x)); }
DEV float tanh_f(float x) {
  return 2.f * fast_rcp(1.f + fast_ex2(-2.8853900817779268f * x)) - 1.f;
}

DEV uint32_t pk_add(uint32_t a, uint32_t b) {
  return __builtin_bit_cast(uint32_t,
      __builtin_bit_cast(half2_t, a) + __builtin_bit_cast(half2_t, b));
}

// w*y + b, packed fp16
DEV uint32_t pk_fma(uint32_t w, uint32_t y, uint32_t b) {
  return __builtin_bit_cast(uint32_t,
      __builtin_bit_cast(half2_t, w) * __builtin_bit_cast(half2_t, y) +
      __builtin_bit_cast(half2_t, b));
}

// relu(w*y + b), packed fp16
DEV uint32_t pk_relufma(uint32_t w, uint32_t y, uint32_t b) {
  half2_t r = __builtin_bit_cast(half2_t, w) * __builtin_bit_cast(half2_t, y) +
              __builtin_bit_cast(half2_t, b);
  half2_t z = {(_Float16)0.f, (_Float16)0.f};
#if __has_builtin(__builtin_elementwise_max)
  r = __builtin_elementwise_max(r, z);
#else
  uint32_t u = __builtin_bit_cast(uint32_t, r);
  uint32_t mask = ((u >> 15) & 1u) * 0xFFFFu | ((u >> 31) & 1u) * 0xFFFF0000u;
  r = __builtin_bit_cast(half2_t, u & ~mask);
#endif
  return __builtin_bit_cast(uint32_t, r);
}

DEV uint32_t cvtpk(float y) {
#if __has_builtin(__builtin_amdgcn_cvt_pkrtz)
  return __builtin_bit_cast(uint32_t, __builtin_amdgcn_cvt_pkrtz(y, y));
#else
  return pack2f(y, y);
#endif
}

// ---------------- workspace layout (bytes) ----------------
static constexpr size_t OFF_XH  = 0;                 // 96*1024*12 u32 = 4,718,592
static constexpr size_t OFF_W0  = 4718592;           // w0A 40960 u32 = 163,840
static constexpr size_t OFF_BS0 = 4882432;           // 512 f32
static constexpr size_t OFF_W1L = 4884480;           // w1A 65536 u32 = 262,144
static constexpr size_t OFF_BS1 = 5146624;           // 512 f32
static constexpr size_t OFF_W2P = 5148672;           // 128*64 u32 = 32,768
static constexpr size_t OFF_ENC = 5181440;           // 1024*128 f32 = 524,288
static constexpr size_t OFF_YS0 = 5705728;           // 96*1024*128 half = 25,165,824
// aliased into the dead xh16 region (xh16 only live until k_lstm0):
static constexpr size_t OFF_BASES = 0;               // half[1024*8*128] = 2,097,152
static constexpr size_t OFF_TPROJ = 2097152;         // half[100*128] = 25,600
static constexpr size_t OFF_CC    = 2122752;         // float2[100] = 800
static constexpr size_t OFF_W1YP  = 2123584;         // u32[64]
static constexpr size_t OFF_W150P = 2123840;         // u32[64]

// ---------------- prep: pack [x_hist | emb] as fp16 pairs ----------------
__global__ void k_prep_xh(const float* __restrict__ xh, const int* __restrict__ tix,
                          const float* __restrict__ temb, uint32_t* __restrict__ out) {
  int idx = blockIdx.x * 256 + threadIdx.x;          // 96*1024*12 total
  if (idx >= 96 * 1024 * 12) return;
  int m = idx % 12;
  int tb = idx / 12;
  int b = tb & 1023, t = tb >> 10;
  int k0 = 2 * m, k1 = k0 + 1;
  float v0 = (k0 < 8) ? xh[(b * 96 + t) * 8 + k0] : temb[tix[b] * 16 + (k0 - 8)];
  float v1 = (k1 < 8) ? xh[(b * 96 + t) * 8 + k1] : temb[tix[b] * 16 + (k1 - 8)];
  out[idx] = pack2f(v0, v1);
}

// ---------------- prep: pack LSTM/W2 weights ----------------
__global__ void k_prep_w(const float* __restrict__ Wih0, const float* __restrict__ Whh0,
                         const float* __restrict__ bih0, const float* __restrict__ bhh0,
                         const float* __restrict__ Wih1, const float* __restrict__ Whh1,
                         const float* __restrict__ bih1, const float* __restrict__ bhh1,
                         const float* __restrict__ W2,
                         uint32_t* __restrict__ w0p, uint32_t* __restrict__ w1p,
                         uint32_t* __restrict__ w2p, float* __restrict__ bs0,
                         float* __restrict__ bs1) {
  int idx = blockIdx.x * 256 + threadIdx.x;
  if (idx < 40960) {                       // w0A: NF=5, K=160 ([x24|h128|pad8])
    int w = idx / 5120;
    int r = idx % 5120;
    int T = r / 1280; r %= 1280;
    int f = r / 256;  r %= 256;
    int l = r >> 2, c = r & 3;
    int m = l & 15, qf = l >> 4;
    int g = (m & 3) * 128 + w * 16 + (m >> 2) * 4 + T;
    int k0 = f * 32 + qf * 8 + 2 * c, k1 = k0 + 1;
    float a = (k0 < 24) ? Wih0[g * 24 + k0] : ((k0 < 152) ? Whh0[g * 128 + k0 - 24] : 0.f);
    float b = (k1 < 24) ? Wih0[g * 24 + k1] : ((k1 < 152) ? Whh0[g * 128 + k1 - 24] : 0.f);
    w0p[idx] = pack2f(a, b);
  } else if (idx < 106496) {               // w1A: NF=8, K=256 ([ys0 128|h128])
    int i = idx - 40960;
    int w = i / 8192;
    int r = i % 8192;
    int T = r / 2048; r %= 2048;
    int f = r / 256;  r %= 256;
    int l = r >> 2, c = r & 3;
    int m = l & 15, qf = l >> 4;
    int g = (m & 3) * 128 + w * 16 + (m >> 2) * 4 + T;
    int k0 = f * 32 + qf * 8 + 2 * c, k1 = k0 + 1;
    float a = (k0 < 128) ? Wih1[g * 128 + k0] : Whh1[g * 128 + k0 - 128];
    float b = (k1 < 128) ? Wih1[g * 128 + k1] : Whh1[g * 128 + k1 - 128];
    w1p[i] = pack2f(a, b);
  } else if (idx < 114688) {               // W2: 128 x 64 u32 (row-major pairs)
    int i = idx - 106496;
    w2p[i] = pack2f(W2[2 * i], W2[2 * i + 1]);
  } else if (idx < 115200) {
    int i = idx - 114688;
    bs0[i] = bih0[i] + bhh0[i];
  } else if (idx < 115712) {
    int i = idx - 115200;
    bs1[i] = bih1[i] + bhh1[i];
  }
}

// ---------------- LSTM layer 0 (MFMA; 16 batch/WG, 64 WGs x 512) ----------------
__global__ __launch_bounds__(512, 2) void k_lstm0(const uint32_t* __restrict__ xh16,
                                                  const uint32_t* __restrict__ w0A,
                                                  const float* __restrict__ bs0,
                                                  __half* __restrict__ ys0) {
  __shared__ __align__(16) __half inb[2][16][160];
  const int tid = threadIdx.x;
  const int w = tid >> 6, l = tid & 63;
  const int n = l & 15, ql = l >> 4;
  const int ju = w * 16 + ql * 4;
  const int bbase = blockIdx.x * 16;

  uint4 Af[4][5];
#pragma unroll
  for (int T = 0; T < 4; T++)
#pragma unroll
    for (int f = 0; f < 5; f++)
      Af[T][f] = ((const uint4*)w0A)[((w * 4 + T) * 5 + f) * 64 + l];
  float bias[4][4];
#pragma unroll
  for (int T = 0; T < 4; T++)
#pragma unroll
    for (int r = 0; r < 4; r++) bias[T][r] = bs0[r * 128 + ju + T];

  for (int i = tid; i < 2560; i += 512) ((uint32_t*)inb)[i] = 0u;
  __syncthreads();
  if (tid < 192) {
    int b = tid / 12, m = tid % 12;
    ((uint32_t*)&inb[0][b][0])[m] = xh16[(0 * 1024 + bbase + b) * 12 + m];
  }
  float cst[4] = {0.f, 0.f, 0.f, 0.f};
  __syncthreads();

  for (int t = 0; t < 96; t++) {
    const int cur = t & 1, nxt = cur ^ 1;
    uint32_t sx = 0;
    int sb = 0, sm = 0;
    if (t < 95 && tid < 192) {
      sb = tid / 12; sm = tid % 12;
      sx = xh16[((t + 1) * 1024 + bbase + sb) * 12 + sm];
    }
    v4f acc[4];
#pragma unroll
    for (int T = 0; T < 4; T++) acc[T] = (v4f){0.f, 0.f, 0.f, 0.f};
#pragma unroll
    for (int f = 0; f < 5; f++) {
      uint4 bu = *(const uint4*)&inb[cur][n][f * 32 + ql * 8];
      v8h Bv = __builtin_bit_cast(v8h, bu);
#pragma unroll
      for (int T = 0; T < 4; T++)
        acc[T] = __builtin_amdgcn_mfma_f32_16x16x32_f16(
            __builtin_bit_cast(v8h, Af[T][f]), Bv, acc[T], 0, 0, 0);
    }
    float hv[4];
#pragma unroll
    for (int T = 0; T < 4; T++) {
      float gi = acc[T][0] + bias[T][0];
      float gf = acc[T][1] + bias[T][1];
      float gg = acc[T][2] + bias[T][2];
      float go = acc[T][3] + bias[T][3];
      float c = sigm(gf) * cst[T] + sigm(gi) * tanh_f(gg);
      cst[T] = c;
      hv[T] = sigm(go) * tanh_f(c);
    }
    uint32_t h01 = pack2f(hv[0], hv[1]), h23 = pack2f(hv[2], hv[3]);
    *(uint2*)&inb[nxt][n][24 + ju] = make_uint2(h01, h23);
    *(uint2*)((__half*)ys0 + (size_t)(t * 1024 + bbase + n) * 128 + ju) = make_uint2(h01, h23);
    if (t < 95 && tid < 192) ((uint32_t*)&inb[nxt][sb][0])[sm] = sx;
    barrier_lds();
  }
}

// ---------------- LSTM layer 1 (MFMA; 16 batch/WG, 64 WGs x 512) ----------------
__global__ __launch_bounds__(512, 2) void k_lstm1(const uint32_t* __restrict__ ys0u,
                                                  const uint32_t* __restrict__ w1A,
                                                  const float* __restrict__ bs1,
                                                  float* __restrict__ enc) {
  __shared__ __align__(16) __half inb[2][16][264];
  const int tid = threadIdx.x;
  const int w = tid >> 6, l = tid & 63;
  const int n = l & 15, ql = l >> 4;
  const int ju = w * 16 + ql * 4;
  const int bbase = blockIdx.x * 16;
  const int sb = tid >> 5, sc = tid & 31;

  uint4 Af[4][8];
#pragma unroll
  for (int T = 0; T < 4; T++)
#pragma unroll
    for (int f = 0; f < 8; f++)
      Af[T][f] = ((const uint4*)w1A)[((w * 4 + T) * 8 + f) * 64 + l];
  float bias[4][4];
#pragma unroll
  for (int T = 0; T < 4; T++)
#pragma unroll
    for (int r = 0; r < 4; r++) bias[T][r] = bs1[r * 128 + ju + T];

  for (int i = tid; i < 4224; i += 512) ((uint32_t*)inb)[i] = 0u;
  __syncthreads();
  {
    uint2 v = ((const uint2*)ys0u)[(size_t)(0 * 1024 + bbase + sb) * 32 + sc];
    *(uint2*)&inb[0][sb][sc * 4] = v;
  }
  float cst[4] = {0.f, 0.f, 0.f, 0.f};
  __syncthreads();

  for (int t = 0; t < 96; t++) {
    const int cur = t & 1, nxt = cur ^ 1;
    uint2 sv = make_uint2(0u, 0u);
    if (t < 95)
      sv = ((const uint2*)ys0u)[(size_t)((t + 1) * 1024 + bbase + sb) * 32 + sc];
    v4f acc[4];
#pragma unroll
    for (int T = 0; T < 4; T++) acc[T] = (v4f){0.f, 0.f, 0.f, 0.f};
#pragma unroll
    for (int f = 0; f < 8; f++) {
      uint4 bu = *(const uint4*)&inb[cur][n][f * 32 + ql * 8];
      v8h Bv = __builtin_bit_cast(v8h, bu);
#pragma unroll
      for (int T = 0; T < 4; T++)
        acc[T] = __builtin_amdgcn_mfma_f32_16x16x32_f16(
            __builtin_bit_cast(v8h, Af[T][f]), Bv, acc[T], 0, 0, 0);
    }
    float hv[4];
#pragma unroll
    for (int T = 0; T < 4; T++) {
      float gi = acc[T][0] + bias[T][0];
      float gf = acc[T][1] + bias[T][1];
      float gg = acc[T][2] + bias[T][2];
      float go = acc[T][3] + bias[T][3];
      float c = sigm(gf) * cst[T] + sigm(gi) * tanh_f(gg);
      cst[T] = c;
      hv[T] = sigm(go) * tanh_f(c);
    }
    *(uint2*)&inb[nxt][n][128 + ju] = make_uint2(pack2f(hv[0], hv[1]), pack2f(hv[2], hv[3]));
    if (t < 95) *(uint2*)&inb[nxt][sb][sc * 4] = sv;
    if (t == 95)
      *(float4*)&enc[(size_t)(bbase + n) * 128 + ju] = make_float4(hv[0], hv[1], hv[2], hv[3]);
    barrier_lds();
  }
}

// ---------------- prep: fold everything static into baseS + tables -------------
// baseS[b][s][k] = b1[k] + W1_enc.enc[b] + W1_emb.emb[b] + W1_exo.xfut[b,s]
//                  + W1_he.te(s)        (fp32 accumulate, stored fp16)
// Round 9: sin/cos tables built once per block in LDS (libm hoist).
__global__ void k_prep_diff(const float* __restrict__ enc, const float* __restrict__ W1,
                            const float* __restrict__ b1, const float* __restrict__ xfut,
                            const float* __restrict__ temb, const int* __restrict__ tix,
                            __half* __restrict__ baseS, __half* __restrict__ tprojG,
                            float2* __restrict__ ccG, uint32_t* __restrict__ w1ypG,
                            uint32_t* __restrict__ w150pG) {
  const int k = threadIdx.x;
  const int b = blockIdx.x;
  if (b < 1024) {
    __shared__ float encL[128];
    __shared__ float embL[16];
    __shared__ float te8[8][16];
    encL[k] = enc[b * 128 + k];
    if (k < 16) embL[k] = temb[tix[b] * 16 + k];
    {
      int s = k >> 4, i = k & 15;     // 128 threads = 8x16 exactly
      float f = expf(-logf(10000.f) * (float)(i & 7) / 8.f);
      float a = (float)s * f;
      te8[s][i] = (i < 8) ? cosf(a) : sinf(a);
    }
    __syncthreads();
    const float* wr = W1 + k * 184;
    float base0 = b1[k];
#pragma unroll 8
    for (int j = 0; j < 128; j++) base0 += wr[j] * encL[j];
#pragma unroll
    for (int i = 0; i < 16; i++) base0 += wr[134 + i] * embL[i];
    for (int s = 0; s < 8; s++) {
      float v = base0;
#pragma unroll
      for (int c = 0; c < 6; c++) v += wr[128 + c] * xfut[(b * 8 + s) * 6 + c];
#pragma unroll
      for (int i = 0; i < 16; i++) v += wr[168 + i] * te8[s][i];
      baseS[(b * 8 + s) * 128 + k] = __float2half_rn(v);
    }
  } else {
    __shared__ float teL[100][16];
    for (int p = k; p < 1600; p += 128) {
      int tt = p >> 4, i = p & 15;
      float f = expf(-logf(10000.f) * (float)(i & 7) / 8.f);
      float a = (float)tt * f;
      teL[tt][i] = (i < 8) ? cosf(a) : sinf(a);
    }
    __syncthreads();
    const float* wr = W1 + k * 184;
    float wte[16];
#pragma unroll
    for (int i = 0; i < 16; i++) wte[i] = wr[152 + i];
    for (int tt = 0; tt < 100; tt++) {
      float sv = 0.f;
#pragma unroll
      for (int i = 0; i < 16; i++) sv += wte[i] * teL[tt][i];
      tprojG[tt * 128 + k] = __float2half_rn(sv);
    }
    if (k < 100) {
      float ab = 1.f, beta = 0.f;
      for (int i = 0; i <= k; i++) {
        beta = 1e-4f + (0.02f - 1e-4f) * (float)i / 99.f;
        ab *= (1.f - beta);
      }
      float cs, cd;
      if (k == 0) { cs = sqrtf(1.f - ab); cd = 1.f / (sqrtf(ab) + 1e-8f); }
      else { cs = beta / (sqrtf(1.f - ab) + 1e-8f); cd = 1.f / (sqrtf(1.f - beta) + 1e-8f); }
      ccG[k] = make_float2(cs, cd);
    }
    if (k < 64) {
      w1ypG[k]  = pack2f(W1[(2 * k) * 184 + 151], W1[(2 * k + 1) * 184 + 151]);
      w150pG[k] = pack2f(W1[(2 * k) * 184 + 150], W1[(2 * k + 1) * 184 + 150]);
    }
  }
}

// ---------------- AR diffusion: 2 waves/WG, 16 batches/WG, 64 WGs --------------
// lane l: batch = l&15, q = l>>4 (k-quarter / C-row group).
// OPERAND SWAP: C[m=hidden j][n=batch] = sum_k W2frag[m][k] * h1frag[k][n].
// W2frag and h1frag have identical lane layouts to the r3-r8 (A,B) pair, so
// the packed registers are unchanged; only the intrinsic argument order flips.
// Wave w owns j-tiles nt=w*4..w*4+3 (j = (w*4+nt')*16 + q*4 + r).
// eps: per-lane 16-elem W3 dot -> shfl_xor(16,32) over q-groups -> 1-float LDS
// exchange between the 2 waves (double-buffered) -> eps in every lane.
__global__ __launch_bounds__(128, 1) void k_diff(
    const float* __restrict__ y0, const float* __restrict__ noise,
    const uint32_t* __restrict__ baseS, const uint32_t* __restrict__ tprojG,
    const float2* __restrict__ ccG, const uint32_t* __restrict__ w1ypG,
    const uint32_t* __restrict__ w150pG, const uint32_t* __restrict__ w2p,
    const float* __restrict__ b2, const float* __restrict__ W3,
    const float* __restrict__ b3, float* __restrict__ out) {
  __shared__ __align__(16) uint32_t tprojL[100 * 64];
  __shared__ float2 ccL[100];
  __shared__ float partL[2][2][16];   // [buf][wave][batch]
  const int tid = threadIdx.x;
  const int w = tid >> 6, l = tid & 63;
  const int m = l & 15, q = l >> 4;
  const int bbase = blockIdx.x * 16;
  const int b = bbase + m;

  // stage tables
  for (int i = tid; i < 1600; i += 128)
    ((uint4*)tprojL)[i] = ((const uint4*)tprojG)[i];
  for (int i = tid; i < 100; i += 128) ccL[i] = ccG[i];

  // per-lane resident weights
  uint4 w1yp4[4], w150p4[4];
#pragma unroll
  for (int f = 0; f < 4; f++) {
    w1yp4[f]  = ((const uint4*)w1ypG)[f * 4 + q];
    w150p4[f] = ((const uint4*)w150pG)[f * 4 + q];
  }
  uint4 Wf[4][4];                      // W2 fragments (unchanged packing)
  const uint4* w2u4 = (const uint4*)w2p;
#pragma unroll
  for (int j = 0; j < 4; j++)
#pragma unroll
    for (int f = 0; f < 4; f++)
      Wf[j][f] = w2u4[((w * 4 + j) * 16 + m) * 16 + f * 4 + q];
  // b2/W3 per-lane along the j rows this lane's C holds: j = (w*4+nt)*16+q*4+r
  v4f b2v4[4];
  float4 w3v4[4];
#pragma unroll
  for (int nt = 0; nt < 4; nt++) {
    float4 bv = *(const float4*)&b2[(w * 4 + nt) * 16 + q * 4];
    b2v4[nt] = (v4f){bv.x, bv.y, bv.z, bv.w};
    w3v4[nt] = *(const float4*)&W3[(w * 4 + nt) * 16 + q * 4];
  }
  const float b3v = b3[0];
  float py = y0[b];
  __syncthreads();

  for (int s = 0; s < 8; s++) {
    // bph = baseS(b,s) + w150*prev_y  (packed fp16, once per AR step)
    uint32_t bph[16];
    {
      uint32_t pyP = cvtpk(py);
#pragma unroll
      for (int f = 0; f < 4; f++) {
        uint4 ba = ((const uint4*)baseS)[(b * 8 + s) * 16 + f * 4 + q];
        bph[f * 4 + 0] = pk_fma(w150p4[f].x, pyP, ba.x);
        bph[f * 4 + 1] = pk_fma(w150p4[f].y, pyP, ba.y);
        bph[f * 4 + 2] = pk_fma(w150p4[f].z, pyP, ba.z);
        bph[f * 4 + 3] = pk_fma(w150p4[f].w, pyP, ba.w);
      }
    }
    float y = noise[s * 1024 + b];

    // preload t=99: bt0 = bph + tproj[99]
    uint32_t bt0[16], bt1[16];
#pragma unroll
    for (int f = 0; f < 4; f++) {
      uint4 tv = *(const uint4*)&tprojL[99 * 64 + f * 16 + q * 4];
      bt0[f * 4 + 0] = pk_add(bph[f * 4 + 0], tv.x);
      bt0[f * 4 + 1] = pk_add(bph[f * 4 + 1], tv.y);
      bt0[f * 4 + 2] = pk_add(bph[f * 4 + 2], tv.z);
      bt0[f * 4 + 3] = pk_add(bph[f * 4 + 3], tv.w);
    }
    float2 ccv = ccL[99];

    // one diffusion step: uses BT, prefetches t-1 into BTN.
#define DIFF_STEP(T_, BT_, BTN_, BUF_)                                          \
    {                                                                           \
      uint32_t yP = cvtpk(y);                                                   \
      v4f acc[4];                                                               \
      _Pragma("unroll")                                                         \
      for (int f = 0; f < 4; f++) {                                             \
        uint4 au;                                                               \
        au.x = pk_relufma(w1yp4[f].x, yP, BT_[f * 4 + 0]);                      \
        au.y = pk_relufma(w1yp4[f].y, yP, BT_[f * 4 + 1]);                      \
        au.z = pk_relufma(w1yp4[f].z, yP, BT_[f * 4 + 2]);                      \
        au.w = pk_relufma(w1yp4[f].w, yP, BT_[f * 4 + 3]);                      \
        v8h Hb = __builtin_bit_cast(v8h, au);                                   \
        _Pragma("unroll")                                                       \
        for (int j = 0; j < 4; j++) {                                           \
          v4f c = (f == 0) ? b2v4[j] : acc[j];                                  \
          acc[j] = __builtin_amdgcn_mfma_f32_16x16x32_f16(                      \
              __builtin_bit_cast(v8h, Wf[j][f]), Hb, c, 0, 0, 0);               \
        }                                                                       \
      }                                                                         \
      const int tn_ = ((T_) > 0) ? (T_) - 1 : 0;                                \
      _Pragma("unroll")                                                         \
      for (int f = 0; f < 4; f++) {                                             \
        uint4 tv = *(const uint4*)&tprojL[tn_ * 64 + f * 16 + q * 4];           \
        BTN_[f * 4 + 0] = pk_add(bph[f * 4 + 0], tv.x);                         \
        BTN_[f * 4 + 1] = pk_add(bph[f * 4 + 1], tv.y);                         \
        BTN_[f * 4 + 2] = pk_add(bph[f * 4 + 2], tv.z);                         \
        BTN_[f * 4 + 3] = pk_add(bph[f * 4 + 3], tv.w);                         \
      }                                                                         \
      float2 ccn = ccL[tn_];                                                    \
      float local = 0.f;                                                        \
      _Pragma("unroll")                                                         \
      for (int j = 0; j < 4; j++) {                                             \
        local += w3v4[j].x * fmaxf(acc[j][0], 0.f);                             \
        local += w3v4[j].y * fmaxf(acc[j][1], 0.f);                             \
        local += w3v4[j].z * fmaxf(acc[j][2], 0.f);                             \
        local += w3v4[j].w * fmaxf(acc[j][3], 0.f);                             \
      }                                                                         \
      local += __shfl_xor(local, 16, 64);                                       \
      local += __shfl_xor(local, 32, 64);                                       \
      if (l < 16) partL[BUF_][w][l] = local;                                    \
      barrier_lds();                                                            \
      float eps = local + partL[BUF_][1 - w][m] + b3v;                          \
      y = (y - ccv.x * eps) * ccv.y;                                            \
      ccv = ccn;                                                                \
    }

    for (int tt = 0; tt < 50; tt++) {
      const int t = 99 - 2 * tt;
      DIFF_STEP(t, bt0, bt1, 0)
      DIFF_STEP(t - 1, bt1, bt0, 1)
    }
#undef DIFF_STEP

    if (w == 0 && l < 16) out[(bbase + l) * 8 + s] = y;
    py = y;
  }
}

// ---------------------------------------------------------------------------
extern "C" void kernel_launch(void* const* d_in, const int* in_sizes, int n_in,
                              void* d_out, int out_size, void* d_ws, size_t ws_size,
                              hipStream_t stream) {
  const float* x_hist    = (const float*)d_in[0];
  const float* x_future  = (const float*)d_in[1];
  const float* y0        = (const float*)d_in[2];
  const int*   turb_idx  = (const int*)d_in[3];
  const float* init_noise = (const float*)d_in[5];
  const float* turb_emb  = (const float*)d_in[6];
  const float* W_ih0     = (const float*)d_in[7];
  const float* W_hh0     = (const float*)d_in[8];
  const float* b_ih0     = (const float*)d_in[9];
  const float* b_hh0     = (const float*)d_in[10];
  const float* W_ih1     = (const float*)d_in[11];
  const float* W_hh1     = (const float*)d_in[12];
  const float* b_ih1     = (const float*)d_in[13];
  const float* b_hh1     = (const float*)d_in[14];
  const float* W1        = (const float*)d_in[15];
  const float* b1        = (const float*)d_in[16];
  const float* W2        = (const float*)d_in[17];
  const float* b2        = (const float*)d_in[18];
  const float* W3        = (const float*)d_in[19];
  const float* b3        = (const float*)d_in[20];

  char* ws = (char*)d_ws;
  uint32_t* xh16 = (uint32_t*)(ws + OFF_XH);
  uint32_t* w0p  = (uint32_t*)(ws + OFF_W0);
  float*    bs0  = (float*)(ws + OFF_BS0);
  uint32_t* w1p  = (uint32_t*)(ws + OFF_W1L);
  float*    bs1  = (float*)(ws + OFF_BS1);
  uint32_t* w2p  = (uint32_t*)(ws + OFF_W2P);
  float*    encf = (float*)(ws + OFF_ENC);
  __half*   ys0h = (__half*)(ws + OFF_YS0);
  // aliased onto the xh16 region (dead after k_lstm0):
  __half*   baseS  = (__half*)(ws + OFF_BASES);
  __half*   tprojG = (__half*)(ws + OFF_TPROJ);
  float2*   ccG    = (float2*)(ws + OFF_CC);
  uint32_t* w1ypG  = (uint32_t*)(ws + OFF_W1YP);
  uint32_t* w150pG = (uint32_t*)(ws + OFF_W150P);

  k_prep_xh<<<4608, 256, 0, stream>>>(x_hist, turb_idx, turb_emb, xh16);
  k_prep_w<<<452, 256, 0, stream>>>(W_ih0, W_hh0, b_ih0, b_hh0,
                                    W_ih1, W_hh1, b_ih1, b_hh1,
                                    W2, w0p, w1p, w2p, bs0, bs1);
  k_lstm0<<<64, 512, 0, stream>>>(xh16, w0p, bs0, ys0h);
  k_lstm1<<<64, 512, 0, stream>>>((const uint32_t*)ys0h, w1p, bs1, encf);
  k_prep_diff<<<1025, 128, 0, stream>>>(encf, W1, b1, x_future, turb_emb, turb_idx,
                                        baseS, tprojG, ccG, w1ypG, w150pG);
  k_diff<<<64, 128, 0, stream>>>(y0, init_noise, (const uint32_t*)baseS,
                                 (const uint32_t*)tprojG, ccG, w1ypG, w150pG,
                                 w2p, b2, W3, b3, (float*)d_out);
}